// Round 19
// baseline (494.534 us; speedup 1.0000x reference)
//
#include <hip/hip_runtime.h>

#define HID   51
#define T_LEN 512
#define BT    4          // batch elems per block -> 2 blocks/CU (phase overlap)
#define NTH   512        // 8 waves (CP packs 2 such blocks; 13-wave blocks don't pack)

// LDS float offsets in the 13312-float (52 KB) arena (staging needs full 208x64).
#define X_OFF   0        // 4 x 516 (zero-padded tail)
#define OUT_OFF 2064     // 4 x 516
#define H_OFF   4128     // unified B: 2 parity x 512 floats
                         // cols 0-3 h1, 4-7 h1-dup (+x@k51), 8-11 h2, 12-15 h2-dup

typedef _Float16 h8 __attribute__((ext_vector_type(8)));
typedef float    f4 __attribute__((ext_vector_type(4)));

__device__ __forceinline__ float fast_rcp(float x) { return __builtin_amdgcn_rcpf(x); }
__device__ __forceinline__ float sigm(float x) { return fast_rcp(1.0f + __expf(-x)); }
__device__ __forceinline__ float tanh_f(float x) {     // clamped (c-state can drift)
    x = fminf(15.0f, fmaxf(-15.0f, x));
    float e = __expf(2.0f * x);
    return (e - 1.0f) * fast_rcp(e + 1.0f);
}
__device__ __forceinline__ float tanh_nc(float x) {    // g-gate: bounded ~8.2
    float e = __expf(2.0f * x);
    return (e - 1.0f) * fast_rcp(e + 1.0f);
}

// lane col<->col^8 swap within each 16-lane row (verified r5-r17; 8 is self-inverse)
__device__ __forceinline__ float dpp_ror8(float v) {
    int t = __builtin_amdgcn_update_dpp(0, __float_as_int(v), 0x128, 0xf, 0xf, true);
    return __int_as_float(t);
}

// read 8 fp32 from LDS, convert to f16
__device__ __forceinline__ h8 cvt_frag1(const float* p) {
    float4 a = *(const float4*)p;
    float4 b = *(const float4*)(p + 4);
    h8 h;
    h[0] = (_Float16)a.x; h[1] = (_Float16)a.y; h[2] = (_Float16)a.z; h[3] = (_Float16)a.w;
    h[4] = (_Float16)b.x; h[5] = (_Float16)b.y; h[6] = (_Float16)b.z; h[7] = (_Float16)b.w;
    return h;
}

__device__ __forceinline__ float gate_update(const float G[4], float& c) {
    float iv = sigm(G[0]), fv = sigm(G[1]), gv = tanh_nc(G[2]), ov = sigm(G[3]);
    c = fv * c + iv * gv;
    return ov * tanh_f(c);
}

#define MFMA16(A, B, C) __builtin_amdgcn_mfma_f32_16x16x32_f16((A), (B), (C), 0, 0, 0)

__global__ __launch_bounds__(NTH, 4)   // 4 waves/SIMD (2 blocks) -> VGPR <= 128
void lstm_seq_kernel(const float* __restrict__ x,
                     const float* __restrict__ W_ih1, const float* __restrict__ b_ih1,
                     const float* __restrict__ W_hh1, const float* __restrict__ b_hh1,
                     const float* __restrict__ W_ih2, const float* __restrict__ b_ih2,
                     const float* __restrict__ W_hh2, const float* __restrict__ b_hh2,
                     const float* __restrict__ fc_w,  const float* __restrict__ fc_b,
                     float* __restrict__ out)
{
    __shared__ __align__(16) float sb[13312];   // 52 KB arena

    const int tid   = threadIdx.x;
    const int b0    = blockIdx.x * BT;
    const int w     = tid >> 6;          // wave id 0..7
    const int lane  = tid & 63;
    const int row16 = lane & 15;
    const int q4    = lane >> 4;
    const int col   = row16;
    const int cq    = col >> 2;          // 0=L1/s0 1=L1/s1 2=L2/s0 3=L2/s1

    // tile slots: {w, w+8} for w<5; waves 5-7 slot1 = tile 12 (dup, benign)
    const int mt0 = w;
    const int mt1 = (w < 5) ? 8 + w : 12;

    // ============ weight staging (r17 code verbatim, ROW-PERMUTED row'=4j+g) ======
    h8 a1f[2][2];    // W_hh1' + W_ih1 folded at k=51        [slot][kt]
    h8 a2if[2][2];   // W_ih2'  (k=51 zero: x must not leak)
    h8 a2hf[2][2];   // W_hh2' + fc_w as permuted row 204 (k=51 zero)

    // image 1: W_hh1 permuted [208][64]; column k=51 carries W_ih1 (x-term)
    for (int i = tid; i < 208 * 64; i += NTH) {
        int rp = i >> 6, k = i & 63;
        int j = rp >> 2, g = rp & 3;
        float v = 0.0f;
        if (j < HID) {
            if (k < HID)       v = W_hh1[(g * HID + j) * HID + k];
            else if (k == HID) v = W_ih1[g * HID + j];
        }
        sb[i] = v;
    }
    __syncthreads();
    #pragma unroll
    for (int s = 0; s < 2; ++s) {
        int mt = s ? mt1 : mt0;
        #pragma unroll
        for (int kt = 0; kt < 2; ++kt)
            a1f[s][kt] = cvt_frag1(sb + (mt * 16 + row16) * 64 + kt * 32 + q4 * 8);
    }
    __syncthreads();

    // image 2: W_ih2 permuted (k=51 zero)
    for (int i = tid; i < 208 * 64; i += NTH) {
        int rp = i >> 6, k = i & 63;
        int j = rp >> 2, g = rp & 3;
        sb[i] = (j < HID && k < HID) ? W_ih2[(g * HID + j) * HID + k] : 0.0f;
    }
    __syncthreads();
    #pragma unroll
    for (int s = 0; s < 2; ++s) {
        int mt = s ? mt1 : mt0;
        #pragma unroll
        for (int kt = 0; kt < 2; ++kt)
            a2if[s][kt] = cvt_frag1(sb + (mt * 16 + row16) * 64 + kt * 32 + q4 * 8);
    }
    __syncthreads();

    // image 3: W_hh2 permuted + fc_w as permuted row 204 (k=51 zero)
    for (int i = tid; i < 208 * 64; i += NTH) {
        int rp = i >> 6, k = i & 63;
        int j = rp >> 2, g = rp & 3;
        float v = 0.0f;
        if (k < HID) {
            if (j < HID)        v = W_hh2[(g * HID + j) * HID + k];
            else if (rp == 204) v = fc_w[k];
        }
        sb[i] = v;
    }
    __syncthreads();
    #pragma unroll
    for (int s = 0; s < 2; ++s) {
        int mt = s ? mt1 : mt0;
        #pragma unroll
        for (int kt = 0; kt < 2; ++kt)
            a2hf[s][kt] = cvt_frag1(sb + (mt * 16 + row16) * 64 + kt * 32 + q4 * 8);
    }
    __syncthreads();

    // ============ per-slot bias C-init vectors ============
    const int jq0 = 4 * mt0 + q4;
    const int jq1 = 4 * mt1 + q4;        // 51 on waves 4-7 q4=3 (x-slot)
    f4 bi1s0, bi1s1, bi2s0, bi2s1;
    #pragma unroll
    for (int g = 0; g < 4; ++g) {
        bi1s0[g] = (jq0 < HID) ? (b_ih1[g * HID + jq0] + b_hh1[g * HID + jq0]) : 0.f;
        bi1s1[g] = (jq1 < HID) ? (b_ih1[g * HID + jq1] + b_hh1[g * HID + jq1]) : 0.f;
        bi2s0[g] = (jq0 < HID) ? (b_ih2[g * HID + jq0] + b_hh2[g * HID + jq0]) : 0.f;
        bi2s1[g] = (jq1 < HID) ? (b_ih2[g * HID + jq1] + b_hh2[g * HID + jq1]) : 0.f;
    }

    // gate task per lane: quad0 (j=jq0,L1) quad1 (j=jq1,L1) quad2 (jq0,L2) quad3 (jq1,L2)
    const int  jsel = (cq & 1) ? jq1 : jq0;
    const bool lay1 = (cq < 2);
    const int  bsel = col & 3;
    const bool val  = (jsel < HID);
    const int  cpos = lay1 ? bsel : (8 + bsel);   // first of the duplicated col pair
    const int  offh = H_OFF * 2
                    + (jsel >> 5) * 512 + ((((jsel & 31) >> 3) << 4) + cpos) * 8 + (jsel & 7);
    // x-writer lanes: (L1, j==51) slots ARE the h1 k=51 x-positions (waves 4-7, q4=3)
    const bool xw = (jsel == HID) && lay1;

    // ============ runtime buffers ============
    float* xl   = sb + X_OFF;    // [b][516], tail zero-padded
    float* outl = sb + OUT_OFF;  // [b][516]
    for (int i = tid; i < BT * 516; i += NTH) {
        int b = i / 516, t = i - 516 * b;
        xl[i] = (t < T_LEN) ? x[(size_t)(b0 + b) * T_LEN + t] : 0.0f;
    }
    for (int i = tid; i < 1024; i += NTH) sb[H_OFF + i] = 0.0f;  // both parities

    float c = 0.f;
    const float fcb = fc_b[0];
    // fc row 204 lives in slot-1 (tile 12) chains, valid at h2-dup cols 12-15;
    // dedup the out-write to wave 5 (waves 4-7 all carry tile 12)
    const bool outlane = (w == 5) && (q4 == 3) && (cq == 3);
    const float* xq  = xl + bsel * 516;
    const float* rA0 = sb + H_OFF + lane * 4;
    _Float16* hwp = (_Float16*)sb + offh;
    __syncthreads();

    // ============ prologue: h1(0) from x(0) (h1(-1)=0); seed x(1); parity 0 ====
    if (lay1) {
        if (val) {
            float xv = xq[0];
            f4 bb = (cq == 0) ? bi1s0 : bi1s1;
            float G[4];
            #pragma unroll
            for (int g = 0; g < 4; ++g)
                G[g] = bb[g] + W_ih1[g * HID + jsel] * xv;
            float hv = gate_update(G, c);
            _Float16 h16 = (_Float16)hv;
            hwp[0] = h16; hwp[32] = h16;          // both duplicated columns
        } else if (xw) {
            _Float16 x16 = (_Float16)xq[1];
            hwp[0] = x16; hwp[32] = x16;
        }
    }
    __syncthreads();

    // ============ recurrence: ONE barrier per body, ror8-only routing ============
    // B parity p: cols 0-3 & 4-7 = h1(i)+x(i+1)@k51 (dup), 8-11 & 12-15 = h2(i-1) (dup)
    //   s0/s1 = bi1 + W_hh1'·B : quad0 reads s0 in-lane, quad1 reads s1 in-lane
    //   u0/u1 = W_ih2'·B ; v0/v1 = bi2 + W_hh2'·B
    //   quad2: G = ror8(u0)+v0 ; quad3: G = ror8(u1)+v1   (ror8 verified r5-r17)
    auto body = [&](int i, int p) {
        const float* rA = rA0 + p * 512;
        h8 bb0 = *(const h8*)(rA);       h8 bb1 = *(const h8*)(rA + 256);

        if (xw) {
            _Float16 x16 = (_Float16)xq[i + 2];
            hwp[(p ^ 1) * 1024] = x16; hwp[(p ^ 1) * 1024 + 32] = x16;
        }

        f4 s0 = bi1s0, s1 = bi1s1;
        s0 = MFMA16(a1f[0][0], bb0, s0); s1 = MFMA16(a1f[1][0], bb0, s1);
        s0 = MFMA16(a1f[0][1], bb1, s0); s1 = MFMA16(a1f[1][1], bb1, s1);
        f4 u0 = {0.f,0.f,0.f,0.f}, u1 = u0;
        u0 = MFMA16(a2if[0][0], bb0, u0); u1 = MFMA16(a2if[1][0], bb0, u1);
        u0 = MFMA16(a2if[0][1], bb1, u0); u1 = MFMA16(a2if[1][1], bb1, u1);
        f4 v0 = bi2s0, v1 = bi2s1;
        v0 = MFMA16(a2hf[0][0], bb0, v0); v1 = MFMA16(a2hf[1][0], bb0, v1);
        v0 = MFMA16(a2hf[0][1], bb1, v0); v1 = MFMA16(a2hf[1][1], bb1, v1);

        float fcv = v1[0];   // wave5/q4=3/cols12-15: row 204 = fc·h2(i-1) (bi2s1=0 there)
        float G[4];
        #pragma unroll
        for (int g = 0; g < 4; ++g) {
            float t2 = dpp_ror8(u0[g]) + v0[g];
            float t3 = dpp_ror8(u1[g]) + v1[g];
            float t01 = (cq == 0) ? s0[g] : s1[g];
            float t23 = (cq == 2) ? t2 : t3;
            G[g] = lay1 ? t01 : t23;
        }
        float hv = gate_update(G, c);
        _Float16 h16 = (_Float16)hv;
        if (val) {
            hwp[(p ^ 1) * 1024] = h16; hwp[(p ^ 1) * 1024 + 32] = h16;
        }
        if (outlane && i >= 1) outl[bsel * 516 + (i - 1)] = fcb + fcv;
        __syncthreads();
    };
    for (int i = 0; i < T_LEN; i += 2) {   // 256 pairs, parity compile-time
        body(i, 0);
        body(i + 1, 1);
    }
    body(T_LEN, 0);                        // tail emits out(511)

    // ---- write outputs (coalesced) ----
    for (int i = tid; i < BT * T_LEN; i += NTH) {
        int b = i >> 9, tt = i & (T_LEN - 1);
        out[(size_t)(b0 + b) * T_LEN + tt] = outl[b * 516 + tt];
    }
}

extern "C" void kernel_launch(void* const* d_in, const int* in_sizes, int n_in,
                              void* d_out, int out_size, void* d_ws, size_t ws_size,
                              hipStream_t stream) {
    const float* x      = (const float*)d_in[0];
    // d_in[1] = future (scalar, always 0 here) -> ignored
    const float* W_ih1  = (const float*)d_in[2];
    const float* b_ih1v = (const float*)d_in[3];
    const float* W_hh1  = (const float*)d_in[4];
    const float* b_hh1v = (const float*)d_in[5];
    const float* W_ih2  = (const float*)d_in[6];
    const float* b_ih2v = (const float*)d_in[7];
    const float* W_hh2  = (const float*)d_in[8];
    const float* b_hh2v = (const float*)d_in[9];
    const float* fc_w   = (const float*)d_in[10];
    const float* fc_b   = (const float*)d_in[11];
    float* out = (float*)d_out;

    dim3 grid(2048 / BT);   // 512 blocks -> 2 x 8-wave blocks per CU
    dim3 block(NTH);
    lstm_seq_kernel<<<grid, block, 0, stream>>>(x, W_ih1, b_ih1v, W_hh1, b_hh1v,
                                                W_ih2, b_ih2v, W_hh2, b_hh2v,
                                                fc_w, fc_b, out);
}

// Round 20
// 378.897 us; speedup vs baseline: 1.3052x; 1.3052x over previous
//
#include <hip/hip_runtime.h>

#define HID   51
#define T_LEN 512
#define BT    8          // batch elems per block
#define NTH   832        // 13 waves: one wave per M-tile (best verified shape, r16)

// LDS float offsets in the 13312-float (52 KB) arena.
#define X_OFF   0        // 8 x 516 (zero-padded tail)
#define H1_OFF  8256     // h1 f16 B-frag: 2 parity x (2 kt x 256 words)
#define H2_OFF  9280     // h2: same (ends 10304 <= 13312)

typedef _Float16 h8 __attribute__((ext_vector_type(8)));
typedef float    f4 __attribute__((ext_vector_type(4)));

__device__ __forceinline__ float fast_rcp(float x) { return __builtin_amdgcn_rcpf(x); }
__device__ __forceinline__ float sigm(float x) { return fast_rcp(1.0f + __expf(-x)); }
// clamped tanh (c-state can drift)
__device__ __forceinline__ float tanh_f(float x) {
    x = fminf(15.0f, fmaxf(-15.0f, x));
    float e = __expf(2.0f * x);
    return (e - 1.0f) * fast_rcp(e + 1.0f);
}
// unclamped tanh (g-gate pre-activation bounded ~8.2)
__device__ __forceinline__ float tanh_nc(float x) {
    float e = __expf(2.0f * x);
    return (e - 1.0f) * fast_rcp(e + 1.0f);
}

// lane col<->col^8 swap within each 16-lane row (self-inverse; verified r5-r17)
__device__ __forceinline__ float dpp_ror8(float v) {
    int t = __builtin_amdgcn_update_dpp(0, __float_as_int(v), 0x128, 0xf, 0xf, true);
    return __int_as_float(t);
}

// read 8 fp32 from LDS, convert to f16
__device__ __forceinline__ h8 cvt_frag1(const float* p) {
    float4 a = *(const float4*)p;
    float4 b = *(const float4*)(p + 4);
    h8 h;
    h[0] = (_Float16)a.x; h[1] = (_Float16)a.y; h[2] = (_Float16)a.z; h[3] = (_Float16)a.w;
    h[4] = (_Float16)b.x; h[5] = (_Float16)b.y; h[6] = (_Float16)b.z; h[7] = (_Float16)b.w;
    return h;
}

__device__ __forceinline__ float gate_update(const float G[4], float& c) {
    float iv = sigm(G[0]), fv = sigm(G[1]), gv = tanh_nc(G[2]), ov = sigm(G[3]);
    c = fv * c + iv * gv;
    return ov * tanh_f(c);
}

#define MFMA16(A, B, C) __builtin_amdgcn_mfma_f32_16x16x32_f16((A), (B), (C), 0, 0, 0)

__global__ __launch_bounds__(NTH)
void lstm_seq_kernel(const float* __restrict__ x,
                     const float* __restrict__ W_ih1, const float* __restrict__ b_ih1,
                     const float* __restrict__ W_hh1, const float* __restrict__ b_hh1,
                     const float* __restrict__ W_ih2, const float* __restrict__ b_ih2,
                     const float* __restrict__ W_hh2, const float* __restrict__ b_hh2,
                     const float* __restrict__ fc_w,  const float* __restrict__ fc_b,
                     float* __restrict__ out)
{
    __shared__ __align__(16) float sb[13312];   // 52 KB arena

    const int tid   = threadIdx.x;
    const int b0    = blockIdx.x * BT;
    const int w     = tid >> 6;          // wave id 0..12 == M-tile id
    const int lane  = tid & 63;
    const int row16 = lane & 15;
    const int q4    = lane >> 4;
    const int col   = row16;             // D col: 0-7 layer-1 tasks, 8-15 layer-2

    // ============ weight staging (ROW-PERMUTED: row' = 4j + gate), f16 ============
    h8 a1f[2];   // L1: W_hh1' with W_ih1 folded in at k=51 (x-column)
    h8 a2f[4];   // L2: [W_ih2' | W_hh2'+fc], K padded 102->128

    // image 1: W_hh1 permuted [208][64]; column k=51 carries W_ih1 (x-term)
    for (int i = tid; i < 208 * 64; i += NTH) {
        int rp = i >> 6, k = i & 63;
        int j = rp >> 2, g = rp & 3;
        float v = 0.0f;
        if (j < HID) {
            if (k < HID)       v = W_hh1[(g * HID + j) * HID + k];
            else if (k == HID) v = W_ih1[g * HID + j];   // x-column (k=51)
        }
        sb[i] = v;
    }
    __syncthreads();
    #pragma unroll
    for (int kt = 0; kt < 2; ++kt)
        a1f[kt] = cvt_frag1(sb + (w * 16 + row16) * 64 + kt * 32 + q4 * 8);
    __syncthreads();

    // image 2: W_ih2 permuted -> L2 k-tiles 0,1 (h1 half; k=51 stays ZERO so
    // the x value living in the h1 B-frag's k=51 slot does not leak into L2)
    for (int i = tid; i < 208 * 64; i += NTH) {
        int rp = i >> 6, k = i & 63;
        int j = rp >> 2, g = rp & 3;
        sb[i] = (j < HID && k < HID) ? W_ih2[(g * HID + j) * HID + k] : 0.0f;
    }
    __syncthreads();
    #pragma unroll
    for (int kt = 0; kt < 2; ++kt)
        a2f[kt] = cvt_frag1(sb + (w * 16 + row16) * 64 + kt * 32 + q4 * 8);
    __syncthreads();

    // image 3: W_hh2 permuted + fc_w as permuted row 204 -> L2 k-tiles 2,3
    for (int i = tid; i < 208 * 64; i += NTH) {
        int rp = i >> 6, k = i & 63;
        int j = rp >> 2, g = rp & 3;
        float v = 0.0f;
        if (k < HID) {
            if (j < HID)        v = W_hh2[(g * HID + j) * HID + k];
            else if (rp == 204) v = fc_w[k];
        }
        sb[i] = v;
    }
    __syncthreads();
    #pragma unroll
    for (int kt = 0; kt < 2; ++kt)
        a2f[kt + 2] = cvt_frag1(sb + (w * 16 + row16) * 64 + kt * 32 + q4 * 8);
    __syncthreads();

    // ============ per-lane constants ============
    const int jq = 4 * w + q4;           // wave's quad hidden index (51 = x-slot)
    f4 bi1, bi2;
    #pragma unroll
    for (int g = 0; g < 4; ++g) {
        bi1[g] = (jq < HID) ? (b_ih1[g * HID + jq] + b_hh1[g * HID + jq]) : 0.f;
        bi2[g] = (jq < HID) ? (b_ih2[g * HID + jq] + b_hh2[g * HID + jq]) : 0.f;
    }
    // gate task: layer = (col>=8)?2:1, batch = col&7, hidden j = jq
    const bool lay1 = (col < 8);
    const int  bsel = col & 7;
    const bool val  = (jq < HID);
    const int offh  = (lay1 ? H1_OFF : H2_OFF) * 2
                    + (jq >> 5) * 512 + ((((jq & 31) >> 3) << 4) + bsel) * 8 + (jq & 7);
    // x-writer lanes: jq==51 on layer-1 side -> h1 B-frag k=51 slot for batch bsel
    const bool xw = (jq == HID) && lay1;

    // ============ runtime buffers ============
    float* xl = sb + X_OFF;    // [b][516], tail zero-padded
    for (int i = tid; i < BT * 516; i += NTH) {
        int b = i / 516, t = i - 516 * b;
        xl[i] = (t < T_LEN) ? x[(size_t)(b0 + b) * T_LEN + t] : 0.0f;
    }
    for (int i = tid; i < 2048; i += NTH) sb[H1_OFF + i] = 0.0f;  // h1+h2, both parities

    float c = 0.f;
    const float fcb = fc_b[0];
    const bool outlane = (w == 12) && (q4 == 3) && (col < 8);
    float* outg = out + (size_t)(b0 + bsel) * T_LEN;   // direct global out base
    const float* xq  = xl + bsel * 516;                // x base (x-writer / prologue)
    const float* rA0 = sb + H1_OFF + lane * 4;         // parity-0 h1 read base
    const float* rB0 = sb + H2_OFF + lane * 4;         // parity-0 h2 read base
    _Float16* hwp = (_Float16*)sb + offh;              // parity-0 scatter base
    __syncthreads();

    // ============ prologue: h1(0) from x(0) (h1(-1)=0); seed x(1); parity 0 ====
    if (lay1) {
        if (val) {
            float xv = xq[0];
            float G[4];
            #pragma unroll
            for (int g = 0; g < 4; ++g)
                G[g] = bi1[g] + W_ih1[g * HID + jq] * xv;
            float hv = gate_update(G, c);
            hwp[0] = (_Float16)hv;
        } else if (xw) {
            hwp[0] = (_Float16)xq[1];     // x(1) into parity-0 k=51 slot
        }
    }
    __syncthreads();

    // ============ recurrence: ONE barrier per body, parity compile-time ============
    // body i: reads h1(i)+x(i+1), h2(i-1) [parity p=i&1]
    //   s chain = W_hh1'.h1(i) + W_ih1.x(i+1) + bias  (x folded at k=51)
    //   u chain = L2 matvec + bias
    //   layer-1 lanes: G = s -> h1(i+1); layer-2 lanes: G = ror8(u) -> h2(i)
    //   x-writer lanes seed x(i+2) into parity p^1; out(i-1) from L2 row 204
    auto body = [&](int i, int p) {
        // x-writer: seed x(i+2) FIRST (targets parity p^1; drains under chains)
        if (xw) hwp[(p ^ 1) * 1024] = (_Float16)xq[i + 2];

        const float* rA = rA0 + p * 512;    // h1(i) + x(i+1)
        const float* rB = rB0 + p * 512;    // h2(i-1)
        h8 bh0 = *(const h8*)(rA);       h8 bh1 = *(const h8*)(rA + 256);
        h8 ch2 = *(const h8*)(rB);       h8 ch3 = *(const h8*)(rB + 256);

        // L1 chain (depth 2), bias in C-init, x-term via k=51
        f4 s = bi1;
        s = MFMA16(a1f[0], bh0, s);
        s = MFMA16(a1f[1], bh1, s);
        // L2 chain (depth 4), bias in C-init
        f4 u = bi2;
        u = MFMA16(a2f[0], bh0, u);
        u = MFMA16(a2f[1], bh1, u);
        u = MFMA16(a2f[2], ch2, u);
        u = MFMA16(a2f[3], ch3, u);

        float fcv = u[0];   // wave12/q4=3/col<8: permuted row 204 = fc . h2(i-1)
        float G[4];
        #pragma unroll
        for (int g = 0; g < 4; ++g) {
            float ur = dpp_ror8(u[g]);
            G[g] = lay1 ? s[g] : ur;
        }
        float hv = gate_update(G, c);
        if (val) hwp[(p ^ 1) * 1024] = (_Float16)hv;
        if (outlane && i >= 1) outg[i - 1] = fcb + fcv;   // direct global store
        __syncthreads();
    };
    for (int i = 0; i < T_LEN; i += 2) {   // 256 unrolled pairs
        body(i, 0);
        body(i + 1, 1);
    }
    body(T_LEN, 0);                        // tail body emits out(511)
}

extern "C" void kernel_launch(void* const* d_in, const int* in_sizes, int n_in,
                              void* d_out, int out_size, void* d_ws, size_t ws_size,
                              hipStream_t stream) {
    const float* x      = (const float*)d_in[0];
    // d_in[1] = future (scalar, always 0 here) -> ignored
    const float* W_ih1  = (const float*)d_in[2];
    const float* b_ih1v = (const float*)d_in[3];
    const float* W_hh1  = (const float*)d_in[4];
    const float* b_hh1v = (const float*)d_in[5];
    const float* W_ih2  = (const float*)d_in[6];
    const float* b_ih2v = (const float*)d_in[7];
    const float* W_hh2  = (const float*)d_in[8];
    const float* b_hh2v = (const float*)d_in[9];
    const float* fc_w   = (const float*)d_in[10];
    const float* fc_b   = (const float*)d_in[11];
    float* out = (float*)d_out;

    dim3 grid(2048 / BT);   // 256 blocks -> 1 block/CU
    dim3 block(NTH);
    lstm_seq_kernel<<<grid, block, 0, stream>>>(x, W_ih1, b_ih1v, W_hh1, b_hh1v,
                                                W_ih2, b_ih2v, W_hh2, b_hh2v,
                                                fc_w, fc_b, out);
}